// Round 6
// baseline (86.712 us; speedup 1.0000x reference)
//
#include <hip/hip_runtime.h>

// STN bilinear sampler: X [16,256,256,64] f32, theta [16,6] f32 -> out [16,256,256,64] f32
// 32x32-pixel tiles split across channels: each block does 32 of 64 channels, so
// 2048 blocks = 8/CU = 32 waves/CU (full occupancy) for more independent memory
// streams in flight. Channel-pair blocks adjacent -> same XCD L2 shares pixel lines.
// Nontemporal stores keep X L3-resident (R4/R5: FETCH ~118MB << X's 268MB).

#define IN_H  256
#define IN_W  256
#define OUT_H 256
#define OUT_W 256
#define NC    64
#define NB    16

#define TILE_R 32    // output rows per block
#define TILE_C 32    // output pixels per row per block
// blocks: 16 batches * (256/32=8) * (256/32=8) * 2 channel-halves = 2048,
// each runs 32 iters of 256 threads (32x32 px * 32 ch / 4ch-groups).

typedef float floatx4 __attribute__((ext_vector_type(4)));  // native vec for nontemporal store

__global__ __launch_bounds__(256) void stn_kernel(const float* __restrict__ X,
                                                  const float* __restrict__ theta,
                                                  float* __restrict__ out) {
    // bijective XCD-chunked swizzle (2048 % 8 == 0): XCD k gets 256 contiguous ids
    // = exactly 2 batch images (both channel-halves of each tile stay on one XCD).
    const int bid = blockIdx.x;
    const int swz = (bid & 7) * 256 + (bid >> 3);

    const int ch_half = swz & 1;      // channel half is the LSB -> pair adjacency
    const int tid6    = swz >> 1;     // 0..1023 spatial tile id
    const int b    = tid6 >> 6;       // 64 spatial tiles per batch image
    const int tile = tid6 & 63;
    const int tr   = tile >> 3;       // 8 tile-rows
    const int tc   = tile & 7;        // 8 tile-cols
    const int base_oh = tr << 5;
    const int base_ow = tc << 5;
    const int base_c  = ch_half << 5; // 0 or 32

    const float* th = theta + b * 6;
    const float t0 = th[0], t1 = th[1], t2 = th[2];
    const float t3 = th[3], t4 = th[4], t5 = th[5];

    const size_t xbase = (size_t)b * (IN_H * IN_W * NC);
    const size_t obase = (size_t)b * (OUT_H * OUT_W * NC);

    const int tid = threadIdx.x;

#pragma unroll 4
    for (int it = 0; it < 32; ++it) {
        const int idx = it * 256 + tid;          // 0..8191 within (tile, ch-half)
        const int cg  = idx & 7;                 // 4-channel group within 32-ch half
        const int pxl = idx >> 3;                // 0..1023 pixel within tile
        const int rr  = pxl >> 5;                // row within tile (row-major sweep)
        const int cc  = pxl & 31;
        const int oh  = base_oh + rr;
        const int ow  = base_ow + cc;

        // linspace(-1,1,256): step 2/255
        const float xc = fmaf((float)ow, 2.0f / 255.0f, -1.0f);
        const float yc = fmaf((float)oh, 2.0f / 255.0f, -1.0f);

        const float sg0 = t0 * xc + t1 * yc + t2;
        const float sg1 = t3 * xc + t4 * yc + t5;
        // source scales by W (not W-1), faithful to reference
        const float x = 0.5f * (sg0 + 1.0f) * (float)IN_W;
        const float y = 0.5f * (sg1 + 1.0f) * (float)IN_H;

        // astype(int32) truncates toward zero; clip AFTER truncation
        const int xi = (int)x;
        const int yi = (int)y;
        const int x0i = min(max(xi,     0), IN_W - 1);
        const int x1i = min(max(xi + 1, 0), IN_W - 1);
        const int y0i = min(max(yi,     0), IN_H - 1);
        const int y1i = min(max(yi + 1, 0), IN_H - 1);

        // weights use the CLIPPED indices cast back to float (faithful)
        const float x0f = (float)x0i, x1f = (float)x1i;
        const float y0f = (float)y0i, y1f = (float)y1i;
        const float wa = (x1f - x) * (y1f - y);
        const float wb = (x1f - x) * (y - y0f);
        const float wc = (x - x0f) * (y1f - y);
        const float wd = (x - x0f) * (y - y0f);

        const int co = base_c + (cg << 2);
        const float* r0 = X + xbase + ((size_t)y0i * IN_W) * NC + co;
        const float* r1 = X + xbase + ((size_t)y1i * IN_W) * NC + co;

        const float4 pa = *(const float4*)(r0 + (size_t)x0i * NC);
        const float4 pc = *(const float4*)(r0 + (size_t)x1i * NC);
        const float4 pb = *(const float4*)(r1 + (size_t)x0i * NC);
        const float4 pd = *(const float4*)(r1 + (size_t)x1i * NC);

        floatx4 o;
        o.x = wa * pa.x + wb * pb.x + wc * pc.x + wd * pd.x;
        o.y = wa * pa.y + wb * pb.y + wc * pc.y + wd * pd.y;
        o.z = wa * pa.z + wb * pb.z + wc * pc.z + wd * pd.z;
        o.w = wa * pa.w + wb * pb.w + wc * pc.w + wd * pd.w;

        floatx4* dst = (floatx4*)(out + obase + (((size_t)oh * OUT_W + ow) * NC) + co);
        __builtin_nontemporal_store(o, dst);
    }
}

extern "C" void kernel_launch(void* const* d_in, const int* in_sizes, int n_in,
                              void* d_out, int out_size, void* d_ws, size_t ws_size,
                              hipStream_t stream) {
    const float* X     = (const float*)d_in[0];
    const float* theta = (const float*)d_in[1];
    float* out         = (float*)d_out;

    const int blocks = NB * (OUT_H / TILE_R) * (OUT_W / TILE_C) * 2;  // 2048
    stn_kernel<<<blocks, 256, 0, stream>>>(X, theta, out);
}

// Round 7
// 82.952 us; speedup vs baseline: 1.0453x; 1.0453x over previous
//
#include <hip/hip_runtime.h>

// STN bilinear sampler: X [16,256,256,64] f32, theta [16,6] f32 -> out [16,256,256,64] f32
// R5 structure (32x32x64ch tiles, quarter-wave reads a full 256B pixel line, waves
// store 1KB contiguous, NT stores keep X L3-resident) but 512-thread blocks:
// 1024 blocks x 512 thr = 8192 waves = exactly full residency (32 waves/CU),
// isolating the occupancy lever without touching locality (R6 lesson).

#define IN_H  256
#define IN_W  256
#define OUT_H 256
#define OUT_W 256
#define NC    64
#define NB    16

#define TILE_R 32    // output rows per block
#define TILE_C 32    // output pixels per row per block
// blocks: 16 batches * (256/32=8) * (256/32=8) = 1024, each 32 iters of 512 thr

typedef float floatx4 __attribute__((ext_vector_type(4)));  // native vec for nontemporal store

__global__ __launch_bounds__(512) void stn_kernel(const float* __restrict__ X,
                                                  const float* __restrict__ theta,
                                                  float* __restrict__ out) {
    // bijective XCD-chunked swizzle (1024 % 8 == 0): XCD k gets 128 contiguous tiles
    // = exactly 2 batch images per XCD.
    const int bid = blockIdx.x;
    const int swz = (bid & 7) * 128 + (bid >> 3);

    const int b    = swz >> 6;        // 64 tiles per batch image
    const int tile = swz & 63;
    const int tr   = tile >> 3;       // 8 tile-rows
    const int tc   = tile & 7;        // 8 tile-cols
    const int base_oh = tr << 5;
    const int base_ow = tc << 5;

    const float* th = theta + b * 6;
    const float t0 = th[0], t1 = th[1], t2 = th[2];
    const float t3 = th[3], t4 = th[4], t5 = th[5];

    const size_t xbase = (size_t)b * (IN_H * IN_W * NC);
    const size_t obase = (size_t)b * (OUT_H * OUT_W * NC);

    const int tid = threadIdx.x;

#pragma unroll 4
    for (int it = 0; it < 32; ++it) {
        const int idx = it * 512 + tid;          // 0..16383 within tile
        const int cg  = idx & 15;                // 4-channel group (16 lanes = 256B line)
        const int pxl = idx >> 4;                // 0..1023 pixel within tile
        const int rr  = pxl >> 5;                // row within tile (row-major sweep)
        const int cc  = pxl & 31;
        const int oh  = base_oh + rr;
        const int ow  = base_ow + cc;

        // linspace(-1,1,256): step 2/255
        const float xc = fmaf((float)ow, 2.0f / 255.0f, -1.0f);
        const float yc = fmaf((float)oh, 2.0f / 255.0f, -1.0f);

        const float sg0 = t0 * xc + t1 * yc + t2;
        const float sg1 = t3 * xc + t4 * yc + t5;
        // source scales by W (not W-1), faithful to reference
        const float x = 0.5f * (sg0 + 1.0f) * (float)IN_W;
        const float y = 0.5f * (sg1 + 1.0f) * (float)IN_H;

        // astype(int32) truncates toward zero; clip AFTER truncation
        const int xi = (int)x;
        const int yi = (int)y;
        const int x0i = min(max(xi,     0), IN_W - 1);
        const int x1i = min(max(xi + 1, 0), IN_W - 1);
        const int y0i = min(max(yi,     0), IN_H - 1);
        const int y1i = min(max(yi + 1, 0), IN_H - 1);

        // weights use the CLIPPED indices cast back to float (faithful)
        const float x0f = (float)x0i, x1f = (float)x1i;
        const float y0f = (float)y0i, y1f = (float)y1i;
        const float wa = (x1f - x) * (y1f - y);
        const float wb = (x1f - x) * (y - y0f);
        const float wc = (x - x0f) * (y1f - y);
        const float wd = (x - x0f) * (y - y0f);

        const int co = cg << 2;
        const float* r0 = X + xbase + ((size_t)y0i * IN_W) * NC + co;
        const float* r1 = X + xbase + ((size_t)y1i * IN_W) * NC + co;

        const float4 pa = *(const float4*)(r0 + (size_t)x0i * NC);
        const float4 pc = *(const float4*)(r0 + (size_t)x1i * NC);
        const float4 pb = *(const float4*)(r1 + (size_t)x0i * NC);
        const float4 pd = *(const float4*)(r1 + (size_t)x1i * NC);

        floatx4 o;
        o.x = wa * pa.x + wb * pb.x + wc * pc.x + wd * pd.x;
        o.y = wa * pa.y + wb * pb.y + wc * pc.y + wd * pd.y;
        o.z = wa * pa.z + wb * pb.z + wc * pc.z + wd * pd.z;
        o.w = wa * pa.w + wb * pb.w + wc * pc.w + wd * pd.w;

        floatx4* dst = (floatx4*)(out + obase + (((size_t)oh * OUT_W + ow) * NC) + co);
        __builtin_nontemporal_store(o, dst);
    }
}

extern "C" void kernel_launch(void* const* d_in, const int* in_sizes, int n_in,
                              void* d_out, int out_size, void* d_ws, size_t ws_size,
                              hipStream_t stream) {
    const float* X     = (const float*)d_in[0];
    const float* theta = (const float*)d_in[1];
    float* out         = (float*)d_out;

    const int blocks = NB * (OUT_H / TILE_R) * (OUT_W / TILE_C);  // 1024
    stn_kernel<<<blocks, 512, 0, stream>>>(X, theta, out);
}

// Round 8
// 81.870 us; speedup vs baseline: 1.0591x; 1.0132x over previous
//
#include <hip/hip_runtime.h>

// STN bilinear sampler: X [16,256,256,64] f32, theta [16,6] f32 -> out [16,256,256,64] f32
// Best config (R5): 32x32x64ch tiles, 1024 blocks x 256 thr, XCD-chunked swizzle,
// quarter-wave reads a full 256B pixel line, NT stores keep X L3-resident
// (FETCH ~117MB << X's 268MB). R6/R7 showed more waves don't help (mixed-stream
// DRAM efficiency bound) -> deeper per-wave ILP via unroll 8 is the last lever.

#define IN_H  256
#define IN_W  256
#define OUT_H 256
#define OUT_W 256
#define NC    64
#define NB    16

#define TILE_R 32    // output rows per block
#define TILE_C 32    // output pixels per row per block
// tiles: 16 batches * (256/32=8) * (256/32=8) = 1024 blocks, 64 iters of 256 thr

typedef float floatx4 __attribute__((ext_vector_type(4)));  // native vec for nontemporal store

__global__ __launch_bounds__(256) void stn_kernel(const float* __restrict__ X,
                                                  const float* __restrict__ theta,
                                                  float* __restrict__ out) {
    // bijective XCD-chunked swizzle (1024 % 8 == 0): XCD k gets 128 contiguous tiles
    // = exactly 2 batch images per XCD.
    const int bid = blockIdx.x;
    const int swz = (bid & 7) * 128 + (bid >> 3);

    const int b    = swz >> 6;        // 64 tiles per batch image
    const int tile = swz & 63;
    const int tr   = tile >> 3;       // 8 tile-rows
    const int tc   = tile & 7;        // 8 tile-cols
    const int base_oh = tr << 5;
    const int base_ow = tc << 5;

    const float* th = theta + b * 6;
    const float t0 = th[0], t1 = th[1], t2 = th[2];
    const float t3 = th[3], t4 = th[4], t5 = th[5];

    const size_t xbase = (size_t)b * (IN_H * IN_W * NC);
    const size_t obase = (size_t)b * (OUT_H * OUT_W * NC);

    const int tid = threadIdx.x;

#pragma unroll 8
    for (int it = 0; it < 64; ++it) {
        const int idx = it * 256 + tid;          // 0..16383 within tile
        const int cg  = idx & 15;                // 4-channel group (16 lanes = 256B line)
        const int pxl = idx >> 4;                // 0..1023 pixel within tile
        const int rr  = pxl >> 5;                // row within tile (row-major sweep)
        const int cc  = pxl & 31;
        const int oh  = base_oh + rr;
        const int ow  = base_ow + cc;

        // linspace(-1,1,256): step 2/255
        const float xc = fmaf((float)ow, 2.0f / 255.0f, -1.0f);
        const float yc = fmaf((float)oh, 2.0f / 255.0f, -1.0f);

        const float sg0 = t0 * xc + t1 * yc + t2;
        const float sg1 = t3 * xc + t4 * yc + t5;
        // source scales by W (not W-1), faithful to reference
        const float x = 0.5f * (sg0 + 1.0f) * (float)IN_W;
        const float y = 0.5f * (sg1 + 1.0f) * (float)IN_H;

        // astype(int32) truncates toward zero; clip AFTER truncation
        const int xi = (int)x;
        const int yi = (int)y;
        const int x0i = min(max(xi,     0), IN_W - 1);
        const int x1i = min(max(xi + 1, 0), IN_W - 1);
        const int y0i = min(max(yi,     0), IN_H - 1);
        const int y1i = min(max(yi + 1, 0), IN_H - 1);

        // weights use the CLIPPED indices cast back to float (faithful)
        const float x0f = (float)x0i, x1f = (float)x1i;
        const float y0f = (float)y0i, y1f = (float)y1i;
        const float wa = (x1f - x) * (y1f - y);
        const float wb = (x1f - x) * (y - y0f);
        const float wc = (x - x0f) * (y1f - y);
        const float wd = (x - x0f) * (y - y0f);

        const int co = cg << 2;
        const float* r0 = X + xbase + ((size_t)y0i * IN_W) * NC + co;
        const float* r1 = X + xbase + ((size_t)y1i * IN_W) * NC + co;

        const float4 pa = *(const float4*)(r0 + (size_t)x0i * NC);
        const float4 pc = *(const float4*)(r0 + (size_t)x1i * NC);
        const float4 pb = *(const float4*)(r1 + (size_t)x0i * NC);
        const float4 pd = *(const float4*)(r1 + (size_t)x1i * NC);

        floatx4 o;
        o.x = wa * pa.x + wb * pb.x + wc * pc.x + wd * pd.x;
        o.y = wa * pa.y + wb * pb.y + wc * pc.y + wd * pd.y;
        o.z = wa * pa.z + wb * pb.z + wc * pc.z + wd * pd.z;
        o.w = wa * pa.w + wb * pb.w + wc * pc.w + wd * pd.w;

        floatx4* dst = (floatx4*)(out + obase + (((size_t)oh * OUT_W + ow) * NC) + co);
        __builtin_nontemporal_store(o, dst);
    }
}

extern "C" void kernel_launch(void* const* d_in, const int* in_sizes, int n_in,
                              void* d_out, int out_size, void* d_ws, size_t ws_size,
                              hipStream_t stream) {
    const float* X     = (const float*)d_in[0];
    const float* theta = (const float*)d_in[1];
    float* out         = (float*)d_out;

    const int blocks = NB * (OUT_H / TILE_R) * (OUT_W / TILE_C);  // 1024
    stn_kernel<<<blocks, 256, 0, stream>>>(X, theta, out);
}

// Round 9
// 80.616 us; speedup vs baseline: 1.0756x; 1.0156x over previous
//
#include <hip/hip_runtime.h>

// STN bilinear sampler: X [16,256,256,64] f32, theta [16,6] f32 -> out [16,256,256,64] f32
// FINAL (R5 config, best measured 80.1 us): 32x32x64ch tiles, 1024 blocks x 256 thr,
// XCD-chunked swizzle, quarter-wave reads a full 256B pixel line, waves store 1KB
// contiguous, NT stores keep X L3-resident (FETCH ~117MB << X's 268MB).
// Tested and flat: 16x32 tiles (R4 83.5), channel-split 8/CU (R6 86.7, worse
// coalescing), 512-thr blocks (R7 83.0), unroll 8 (R8 81.9). Structural limit:
// 262MB irreducible write + ~116MB L3-miss read residue at mixed-stream DRAM
// efficiency; already beats the 537MB D2D copy ceiling (~85us @ 6.3TB/s).

#define IN_H  256
#define IN_W  256
#define OUT_H 256
#define OUT_W 256
#define NC    64
#define NB    16

#define TILE_R 32    // output rows per block
#define TILE_C 32    // output pixels per row per block
// tiles: 16 batches * (256/32=8) * (256/32=8) = 1024 blocks, 64 iters of 256 thr

typedef float floatx4 __attribute__((ext_vector_type(4)));  // native vec for nontemporal store

__global__ __launch_bounds__(256) void stn_kernel(const float* __restrict__ X,
                                                  const float* __restrict__ theta,
                                                  float* __restrict__ out) {
    // bijective XCD-chunked swizzle (1024 % 8 == 0): XCD k gets 128 contiguous tiles
    // = exactly 2 batch images per XCD.
    const int bid = blockIdx.x;
    const int swz = (bid & 7) * 128 + (bid >> 3);

    const int b    = swz >> 6;        // 64 tiles per batch image
    const int tile = swz & 63;
    const int tr   = tile >> 3;       // 8 tile-rows
    const int tc   = tile & 7;        // 8 tile-cols
    const int base_oh = tr << 5;
    const int base_ow = tc << 5;

    const float* th = theta + b * 6;
    const float t0 = th[0], t1 = th[1], t2 = th[2];
    const float t3 = th[3], t4 = th[4], t5 = th[5];

    const size_t xbase = (size_t)b * (IN_H * IN_W * NC);
    const size_t obase = (size_t)b * (OUT_H * OUT_W * NC);

    const int tid = threadIdx.x;

#pragma unroll 4
    for (int it = 0; it < 64; ++it) {
        const int idx = it * 256 + tid;          // 0..16383 within tile
        const int cg  = idx & 15;                // 4-channel group (16 lanes = 256B line)
        const int pxl = idx >> 4;                // 0..1023 pixel within tile
        const int rr  = pxl >> 5;                // row within tile (row-major sweep)
        const int cc  = pxl & 31;
        const int oh  = base_oh + rr;
        const int ow  = base_ow + cc;

        // linspace(-1,1,256): step 2/255
        const float xc = fmaf((float)ow, 2.0f / 255.0f, -1.0f);
        const float yc = fmaf((float)oh, 2.0f / 255.0f, -1.0f);

        const float sg0 = t0 * xc + t1 * yc + t2;
        const float sg1 = t3 * xc + t4 * yc + t5;
        // source scales by W (not W-1), faithful to reference
        const float x = 0.5f * (sg0 + 1.0f) * (float)IN_W;
        const float y = 0.5f * (sg1 + 1.0f) * (float)IN_H;

        // astype(int32) truncates toward zero; clip AFTER truncation
        const int xi = (int)x;
        const int yi = (int)y;
        const int x0i = min(max(xi,     0), IN_W - 1);
        const int x1i = min(max(xi + 1, 0), IN_W - 1);
        const int y0i = min(max(yi,     0), IN_H - 1);
        const int y1i = min(max(yi + 1, 0), IN_H - 1);

        // weights use the CLIPPED indices cast back to float (faithful)
        const float x0f = (float)x0i, x1f = (float)x1i;
        const float y0f = (float)y0i, y1f = (float)y1i;
        const float wa = (x1f - x) * (y1f - y);
        const float wb = (x1f - x) * (y - y0f);
        const float wc = (x - x0f) * (y1f - y);
        const float wd = (x - x0f) * (y - y0f);

        const int co = cg << 2;
        const float* r0 = X + xbase + ((size_t)y0i * IN_W) * NC + co;
        const float* r1 = X + xbase + ((size_t)y1i * IN_W) * NC + co;

        const float4 pa = *(const float4*)(r0 + (size_t)x0i * NC);
        const float4 pc = *(const float4*)(r0 + (size_t)x1i * NC);
        const float4 pb = *(const float4*)(r1 + (size_t)x0i * NC);
        const float4 pd = *(const float4*)(r1 + (size_t)x1i * NC);

        floatx4 o;
        o.x = wa * pa.x + wb * pb.x + wc * pc.x + wd * pd.x;
        o.y = wa * pa.y + wb * pb.y + wc * pc.y + wd * pd.y;
        o.z = wa * pa.z + wb * pb.z + wc * pc.z + wd * pd.z;
        o.w = wa * pa.w + wb * pb.w + wc * pc.w + wd * pd.w;

        floatx4* dst = (floatx4*)(out + obase + (((size_t)oh * OUT_W + ow) * NC) + co);
        __builtin_nontemporal_store(o, dst);
    }
}

extern "C" void kernel_launch(void* const* d_in, const int* in_sizes, int n_in,
                              void* d_out, int out_size, void* d_ws, size_t ws_size,
                              hipStream_t stream) {
    const float* X     = (const float*)d_in[0];
    const float* theta = (const float*)d_in[1];
    float* out         = (float*)d_out;

    const int blocks = NB * (OUT_H / TILE_R) * (OUT_W / TILE_C);  // 1024
    stn_kernel<<<blocks, 256, 0, stream>>>(X, theta, out);
}